// Round 15
// baseline (389.674 us; speedup 1.0000x reference)
//
#include <hip/hip_runtime.h>
#include <stdint.h>

typedef unsigned short u16;
typedef unsigned int u32;
typedef unsigned long long u64;
typedef __attribute__((ext_vector_type(2))) float f32x2;
typedef __attribute__((ext_vector_type(4))) float f32x4;
typedef __attribute__((ext_vector_type(8))) short s16x8;
typedef __attribute__((ext_vector_type(4))) u16 u16x4;
typedef __attribute__((ext_vector_type(2))) u32 u32x2;
typedef __attribute__((ext_vector_type(4))) u32 u32x4;

#define NS 50
#define NH 128
#define NPB 16      // batches per block (persistent loop)

// k3 LDS layout (bytes):
//   hidden_tr dbuf: 2 x (8 hc x 14 tiles x 128B) = 28672
//   M_sh: 50 rows x 512B, col-swizzled by ((s&7)<<4) = 25600
//   rs dbuf: 2 x 2 x 64 f32 = 1024
#define HTB 14336
#define HTP 1792
#define M_OFF  28672
#define RS_OFF 54272
#define LDS_TOTAL 55296

// ---------- helpers ----------
__device__ __forceinline__ u16 f2bf(float f) {
  u32 u = __builtin_bit_cast(u32, f);
  u32 r = (u + 0x7FFFu + ((u >> 16) & 1u)) >> 16;
  return (u16)r;
}
__device__ __forceinline__ float bf2f(u16 u) {
  return __builtin_bit_cast(float, (u32)u << 16);
}
__device__ __forceinline__ float sigm(float x) { return 1.0f / (1.0f + __expf(-x)); }
__device__ __forceinline__ float tanh_(float x) { return 1.0f - 2.0f / (1.0f + __expf(2.0f * x)); }
__device__ __forceinline__ s16x8 pack8_trunc(f32x4 a, f32x4 b) {
  u32x4 ua = __builtin_bit_cast(u32x4, a);
  u32x4 ub = __builtin_bit_cast(u32x4, b);
  u32x4 t;
  t[0] = __builtin_amdgcn_perm(ua[1], ua[0], 0x07060302u);
  t[1] = __builtin_amdgcn_perm(ua[3], ua[2], 0x07060302u);
  t[2] = __builtin_amdgcn_perm(ub[1], ub[0], 0x07060302u);
  t[3] = __builtin_amdgcn_perm(ub[3], ub[2], 0x07060302u);
  return __builtin_bit_cast(s16x8, t);
}
// two tr-reads -> one K=32 A-fragment ([4t][16h] tiles, col=(addr>>3)&15)
__device__ __forceinline__ s16x8 afrag_tr2(const unsigned char* p) {
  u32x2 a, b;
  asm volatile(
      "ds_read_b64_tr_b16 %0, %2\n\t"
      "ds_read_b64_tr_b16 %1, %2 offset:128\n\t"
      "s_waitcnt lgkmcnt(0)"
      : "=&v"(a), "=&v"(b)
      : "v"((const __attribute__((address_space(3))) unsigned char*)p)
      : "memory");
  __builtin_amdgcn_sched_barrier(0);
  u32x4 t; t[0] = a[0]; t[1] = a[1]; t[2] = b[0]; t[3] = b[1];
  return __builtin_bit_cast(s16x8, t);
}
// A-out B-fragment direct from global (8B-aligned f32x2 pairs, masked at col 99)
__device__ __forceinline__ s16x8 load_outfrag(const float* ap, int kbase) {
  f32x4 x = {0.f, 0.f, 0.f, 0.f}, y = {0.f, 0.f, 0.f, 0.f};
  const float* p = ap + 50 + kbase;
  if (kbase <= 40) {
    f32x2 a0 = *(const f32x2*)(p);
    f32x2 a1 = *(const f32x2*)(p + 2);
    f32x2 a2 = *(const f32x2*)(p + 4);
    f32x2 a3 = *(const f32x2*)(p + 6);
    x[0] = a0[0]; x[1] = a0[1]; x[2] = a1[0]; x[3] = a1[1];
    y[0] = a2[0]; y[1] = a2[1]; y[2] = a3[0]; y[3] = a3[1];
  } else if (kbase == 48) {
    f32x2 a0 = *(const f32x2*)(p);   // cols 98,99
    x[0] = a0[0]; x[1] = a0[1];
  }
  return pack8_trunc(x, y);
}

// Upack position for element U[j][k]
__device__ __forceinline__ int upack_pos(int j, int k) {
  int kt4 = k >> 5, g4 = (k >> 3) & 3, e2 = k & 7;
  int chunk;
  if (j < 768) {
    int big = j >= 384;
    int jj = j - big * 384;
    int gate = jj >> 7, jr = jj & 127;
    chunk = ((big * 3 + gate) * 8 + (jr >> 4)) * 4 + kt4;
    return chunk * 512 + ((g4 * 16 + (jr & 15)) * 8 + e2);
  } else {
    int jj = j - 768;
    int gate = jj >> 7, jr = jj & 127;
    chunk = 192 + (gate * 8 + (jr >> 4)) * 4 + kt4;
    return chunk * 512 + ((g4 * 16 + (jr & 15)) * 8 + e2);
  }
}

// ---- staging helpers (batch -> hidden_tr buffer) ----
__device__ __forceinline__ void stage_issue(const int* __restrict__ inp,
                                            const float* __restrict__ emb,
                                            f32x4 ev[7], int tid) {
  #pragma unroll
  for (int i2 = 0; i2 < 7; ++i2) {
    int slot = i2 * 256 + tid;
    if (slot < 1600) {
      int t = slot >> 5, hch = slot & 31;
      int node = inp[t];
      ev[i2] = *(const f32x4*)(emb + (size_t)node * NH + hch * 4);
    }
  }
}
__device__ __forceinline__ void stage_write(unsigned char* hb, const f32x4 ev[7], int tid) {
  #pragma unroll
  for (int i2 = 0; i2 < 7; ++i2) {
    int slot = i2 * 256 + tid;
    if (slot < 1600) {
      int t = slot >> 5, hch = slot & 31;
      u32 lo = (u32)f2bf(ev[i2][0]) | ((u32)f2bf(ev[i2][1]) << 16);
      u32 hi = (u32)f2bf(ev[i2][2]) | ((u32)f2bf(ev[i2][3]) << 16);
      u32x2 pv = {lo, hi};
      *(u32x2*)(hb + (hch >> 2) * HTP + (t >> 2) * 128 + (t & 3) * 32 + (hch & 3) * 8) = pv;
    }
  }
}
__device__ __forceinline__ void rowsums_calc(const float* __restrict__ Aq,
                                             float* rsout, int tid) {
  if (tid < 100) {
    int s = tid < 50 ? tid : tid - 50;
    const float* ap = Aq + s * 100;
    float sum;
    if (tid < 50) {
      f32x4 a4 = *(const f32x4*)ap;
      #pragma unroll
      for (int p = 1; p < 12; ++p) a4 += *(const f32x4*)(ap + p * 4);
      f32x4 vt = *(const f32x4*)(ap + 48);
      sum = (a4[0] + a4[1]) + (a4[2] + a4[3]) + vt[0] + vt[1];
    } else {
      f32x4 vt = *(const f32x4*)(ap + 48);
      f32x4 a4 = *(const f32x4*)(ap + 52);
      #pragma unroll
      for (int p = 1; p < 12; ++p) a4 += *(const f32x4*)(ap + 52 + p * 4);
      sum = (a4[0] + a4[1]) + (a4[2] + a4[3]) + vt[2] + vt[3];
    }
    rsout[(tid < 50 ? 0 : 64) + s] = sum;
  }
}

// ---------- kernel 1: fold weights -> Upack (fragment-ordered) + cvec[3][384] f32 ----------
__global__ __launch_bounds__(256) void k1_prep(
    const float* __restrict__ W_in, const float* __restrict__ b_in,
    const float* __restrict__ W_out, const float* __restrict__ b_out,
    const float* __restrict__ w_ih, const float* __restrict__ b_ih,
    const float* __restrict__ w_hh,
    const float* __restrict__ b_iah, const float* __restrict__ b_oah,
    u16* __restrict__ Upk, float* __restrict__ cvec)
{
  int e = blockIdx.x * 256 + threadIdx.x;
  if (e < 147456) {
    int j = e >> 7, k = e & 127;
    float s = 0.f;
    if (j < 768) {
      const float* wr = w_ih + (size_t)(j < 384 ? j : j - 384) * 256 + (j < 384 ? 0 : 128);
      const float* Wc = (j < 384 ? W_in : W_out) + k;
      #pragma unroll 8
      for (int h = 0; h < 128; ++h) s += wr[h] * Wc[h * 128];
    } else {
      s = w_hh[(size_t)(j - 768) * 128 + k];
    }
    Upk[upack_pos(j, k)] = f2bf(s);
  } else if (e < 147456 + 1152) {
    int e2 = e - 147456;
    int which = e2 / 384, g = e2 - which * 384;
    const float* wr = w_ih + (size_t)g * 256;
    float s = 0.f;
    if (which == 0) { for (int h = 0; h < 128; ++h) s += wr[h] * b_in[h]; }
    else if (which == 1) { for (int h = 0; h < 128; ++h) s += wr[128 + h] * b_out[h]; }
    else {
      for (int h = 0; h < 128; ++h) s += wr[h] * b_iah[h] + wr[128 + h] * b_oah[h];
      s += b_ih[g];
    }
    cvec[which * 384 + g] = s;
  }
}

// ---------- kernel 3 (v13): persistent blocks, U resident in registers ----------
// grid 512 = 256 strips x 2 h-halves; block loops over 16 batches.
// Wave w owns h-cols [hh*64+16w, +16): its 36 U fragments (144 VGPR) loaded once.
// Per batch: {issue stage(i+1), rowsums(i+1)} -> GEMM1(i) -> bar -> GEMM2/3(i)
// from regs -> epilogue(i) -> write hidden(i+1) -> bar.
__global__ __launch_bounds__(256, 1) void k3_main(
    const int* __restrict__ inputs, const float* __restrict__ A,
    const u16* __restrict__ Upk, const float* __restrict__ cvec,
    const float* __restrict__ emb, const float* __restrict__ b_hh,
    float* __restrict__ out)
{
  __shared__ __align__(128) unsigned char Sb[LDS_TOTAL];

  const int tid = threadIdx.x;
  const int strip = blockIdx.x >> 1;
  const int hh = blockIdx.x & 1;
  const int w = tid >> 6, l = tid & 63;
  const int l16 = l & 15, g4 = l >> 4;
  const int js = hh * 4 + w;

  // ---- U fragments resident in registers (36 x 16B/lane, coalesced) ----
  const u16* upLane = Upk + (size_t)l * 8;
  s16x8 Au2[2][3][4];
  #pragma unroll
  for (int big = 0; big < 2; ++big)
    #pragma unroll
    for (int gate = 0; gate < 3; ++gate)
      #pragma unroll
      for (int kt4 = 0; kt4 < 4; ++kt4)
        Au2[big][gate][kt4] =
            *(const s16x8*)(upLane + (size_t)(((big * 3 + gate) * 8 + js) * 4 + kt4) * 512);
  s16x8 Au3[3][4];
  #pragma unroll
  for (int gate = 0; gate < 3; ++gate)
    #pragma unroll
    for (int kt = 0; kt < 4; ++kt)
      Au3[gate][kt] = *(const s16x8*)(upLane + (size_t)(192 + (gate * 8 + js) * 4 + kt) * 512);

  // ---- zero hidden_tr tails t 50..55, both buffers ----
  if (tid < 192) {
    int q = tid / 96, r2 = tid - q * 96;
    int hc = r2 / 12, off = (r2 - hc * 12) * 16;
    u32x4 z = {0, 0, 0, 0};
    *(u32x4*)(Sb + q * HTB + hc * HTP + 1600 + off) = z;
  }

  float* rsB = (float*)(Sb + RS_OFF);

  // ---- prologue: stage batch 0 -> buf0, rowsums -> rs[0] ----
  {
    const int b0 = strip * NPB;
    f32x4 ev0[7];
    stage_issue(inputs + (size_t)b0 * NS, emb, ev0, tid);
    rowsums_calc(A + (size_t)b0 * 5000, rsB, tid);
    stage_write(Sb, ev0, tid);
  }
  __syncthreads();

  const s16x8 zero8 = {0, 0, 0, 0, 0, 0, 0, 0};

  for (int i = 0; i < NPB; ++i) {
    const int b = strip * NPB + i;
    const int cur = i & 1;
    unsigned char* hbCur = Sb + cur * HTB;
    const float* Aq = A + (size_t)b * 5000;
    const bool more = (i + 1 < NPB);

    // ---- issue next batch's gather + rowsums (latency hides under GEMMs) ----
    f32x4 ev[7];
    if (more) {
      stage_issue(inputs + (size_t)(b + 1) * NS, emb, ev, tid);
      rowsums_calc(A + (size_t)(b + 1) * 5000, rsB + (1 - cur) * 128, tid);
    }

    // ---- GEMM1: M = A_ext @ hidden -> M_sh ----
    s16x8 BfIn[4][2];
    #pragma unroll
    for (int nt = 0; nt < 4; ++nt) {
      int s = nt * 16 + l16; if (s > NS - 1) s = NS - 1;
      const float* ap = Aq + s * 100;
      {
        f32x4 x = *(const f32x4*)(ap + g4 * 8);
        f32x4 y = *(const f32x4*)(ap + g4 * 8 + 4);
        BfIn[nt][0] = pack8_trunc(x, y);
      }
      {
        f32x4 x = *(const f32x4*)(ap + 32 + g4 * 8);
        f32x4 y = *(const f32x4*)(ap + 32 + g4 * 8 + 4);
        int tb = 32 + g4 * 8;
        #pragma unroll
        for (int j = 0; j < 4; ++j) {
          if (tb + j >= NS) x[j] = 0.f;
          if (tb + 4 + j >= NS) y[j] = 0.f;
        }
        BfIn[nt][1] = pack8_trunc(x, y);
      }
    }
    #pragma unroll
    for (int ht2 = 0; ht2 < 2; ++ht2) {
      const int htile = w * 2 + ht2;
      f32x4 accM[2][4] = {};
      #pragma unroll
      for (int kt = 0; kt < 2; ++kt) {
        const bool ztail = (kt == 1) && (g4 == 3);
        int tile = kt * 8 + 2 * g4;
        s16x8 Af = afrag_tr2(hbCur + htile * HTP + (ztail ? 0 : tile * 128) + l16 * 8);
        if (ztail) Af = zero8;
        #pragma unroll
        for (int nt = 0; nt < 4; ++nt)
          accM[0][nt] = __builtin_amdgcn_mfma_f32_16x16x32_bf16(Af, BfIn[nt][kt], accM[0][nt], 0, 0, 0);
        #pragma unroll
        for (int nt = 0; nt < 4; ++nt) {
          int s = nt * 16 + l16; if (s > NS - 1) s = NS - 1;
          s16x8 Bo = load_outfrag(Aq + s * 100, kt * 32 + g4 * 8);
          accM[1][nt] = __builtin_amdgcn_mfma_f32_16x16x32_bf16(Af, Bo, accM[1][nt], 0, 0, 0);
        }
      }
      #pragma unroll
      for (int mo = 0; mo < 2; ++mo)
        #pragma unroll
        for (int nt = 0; nt < 4; ++nt) {
          int s = nt * 16 + l16;
          if (s < NS) {
            u32 colb = (u32)((mo * 128 + htile * 16 + g4 * 4) * 2);
            u32 swz = (u32)((s & 7) << 4);
            u32 lo = (u32)f2bf(accM[mo][nt][0]) | ((u32)f2bf(accM[mo][nt][1]) << 16);
            u32 hi = (u32)f2bf(accM[mo][nt][2]) | ((u32)f2bf(accM[mo][nt][3]) << 16);
            u32x2 pv = {lo, hi};
            *(u32x2*)(Sb + M_OFF + s * 512 + (colb ^ swz)) = pv;
          }
        }
    }
    __syncthreads();

    // ---- GEMM2 (gi) + GEMM3 (gh), U from registers ----
    f32x4 accRI[2][4] = {};
    f32x4 accN2[4] = {};
    f32x4 accN3[4] = {};
    __builtin_amdgcn_s_setprio(1);
    #pragma unroll
    for (int kt = 0; kt < 8; ++kt) {
      s16x8 Bm[4];
      #pragma unroll
      for (int nt = 0; nt < 4; ++nt) {
        int s = nt * 16 + l16; if (s > NS - 1) s = NS - 1;
        Bm[nt] = *(const s16x8*)(Sb + M_OFF + s * 512 +
                                 ((u32)(kt * 64 + g4 * 16) ^ (u32)((s & 7) << 4)));
      }
      const int big = kt >> 2, kt4 = kt & 3;
      #pragma unroll
      for (int nt = 0; nt < 4; ++nt)
        accRI[0][nt] = __builtin_amdgcn_mfma_f32_16x16x32_bf16(Au2[big][0][kt4], Bm[nt], accRI[0][nt], 0, 0, 0);
      #pragma unroll
      for (int nt = 0; nt < 4; ++nt)
        accRI[1][nt] = __builtin_amdgcn_mfma_f32_16x16x32_bf16(Au2[big][1][kt4], Bm[nt], accRI[1][nt], 0, 0, 0);
      #pragma unroll
      for (int nt = 0; nt < 4; ++nt)
        accN2[nt] = __builtin_amdgcn_mfma_f32_16x16x32_bf16(Au2[big][2][kt4], Bm[nt], accN2[nt], 0, 0, 0);
    }
    #pragma unroll
    for (int kt = 0; kt < 4; ++kt) {
      s16x8 Bh[4];
      #pragma unroll
      for (int nt = 0; nt < 4; ++nt) {
        int s = nt * 16 + l16; if (s > NS - 1) s = NS - 1;
        int h = kt * 32 + g4 * 8;
        Bh[nt] = *(const s16x8*)(hbCur + (h >> 4) * HTP + (s >> 2) * 128 +
                                 (s & 3) * 32 + (h & 15) * 2);
      }
      #pragma unroll
      for (int nt = 0; nt < 4; ++nt)
        accRI[0][nt] = __builtin_amdgcn_mfma_f32_16x16x32_bf16(Au3[0][kt], Bh[nt], accRI[0][nt], 0, 0, 0);
      #pragma unroll
      for (int nt = 0; nt < 4; ++nt)
        accRI[1][nt] = __builtin_amdgcn_mfma_f32_16x16x32_bf16(Au3[1][kt], Bh[nt], accRI[1][nt], 0, 0, 0);
      #pragma unroll
      for (int nt = 0; nt < 4; ++nt)
        accN3[nt] = __builtin_amdgcn_mfma_f32_16x16x32_bf16(Au3[2][kt], Bh[nt], accN3[nt], 0, 0, 0);
    }
    __builtin_amdgcn_s_setprio(0);

    // ---- GRU epilogue ----
    const int h0 = hh * 64 + w * 16 + g4 * 4;
    f32x4 cin[3], cou[3], cz[3], bh[3];
    #pragma unroll
    for (int gate = 0; gate < 3; ++gate) {
      int g = gate * 128 + h0;
      cin[gate] = *(const f32x4*)(cvec + g);
      cou[gate] = *(const f32x4*)(cvec + 384 + g);
      cz[gate]  = *(const f32x4*)(cvec + 768 + g);
      bh[gate]  = *(const f32x4*)(b_hh + g);
    }
    const float* rsC = rsB + cur * 128;
    #pragma unroll
    for (int nt = 0; nt < 4; ++nt) {
      int s = nt * 16 + l16;
      int sc = s > NS - 1 ? NS - 1 : s;
      u16x4 hid4 = *(const u16x4*)(hbCur + (h0 >> 4) * HTP + (sc >> 2) * 128 +
                                   (sc & 3) * 32 + (h0 & 15) * 2);
      float rin = rsC[sc], rou = rsC[64 + sc];
      f32x4 res;
      #pragma unroll
      for (int e = 0; e < 4; ++e) {
        float vr = accRI[0][nt][e] + rin * cin[0][e] + rou * cou[0][e] + cz[0][e] + bh[0][e];
        float vi = accRI[1][nt][e] + rin * cin[1][e] + rou * cou[1][e] + cz[1][e] + bh[1][e];
        float vn = accN2[nt][e] + rin * cin[2][e] + rou * cou[2][e] + cz[2][e];
        float gn_ = accN3[nt][e] + bh[2][e];
        float rr = sigm(vr);
        float ii = sigm(vi);
        float nn = tanh_(vn + rr * gn_);
        res[e] = nn + ii * (bf2f(hid4[e]) - nn);
      }
      if (s < NS)
        *(f32x4*)(out + ((size_t)b * NS + s) * NH + h0) = res;
    }

    // ---- write next batch's hidden into the other buffer ----
    if (more) stage_write(Sb + (1 - cur) * HTB, ev, tid);
    __syncthreads();
  }
}

// ---------- launcher ----------
extern "C" void kernel_launch(void* const* d_in, const int* in_sizes, int n_in,
                              void* d_out, int out_size, void* d_ws, size_t ws_size,
                              hipStream_t stream) {
  const int*   inputs = (const int*)  d_in[0];
  const float* A      = (const float*)d_in[1];
  const float* emb    = (const float*)d_in[2];
  const float* W_in   = (const float*)d_in[3];
  const float* b_in   = (const float*)d_in[4];
  const float* W_out  = (const float*)d_in[5];
  const float* b_out  = (const float*)d_in[6];
  const float* w_ih   = (const float*)d_in[7];
  const float* b_ih   = (const float*)d_in[8];
  const float* w_hh   = (const float*)d_in[9];
  const float* b_hh   = (const float*)d_in[10];
  const float* b_iah  = (const float*)d_in[11];
  const float* b_oah  = (const float*)d_in[12];

  // ws layout: Upk (1152*128 bf16 = 294,912 B, fragment-ordered) | cvec (4,608 B)
  u16*   Upk  = (u16*)d_ws;
  float* cvec = (float*)((char*)d_ws + 294912);

  k1_prep<<<dim3(581), dim3(256), 0, stream>>>(W_in, b_in, W_out, b_out, w_ih, b_ih,
                                               w_hh, b_iah, b_oah, Upk, cvec);
  k3_main<<<dim3(512), dim3(256), 0, stream>>>(inputs, A, Upk, cvec, emb, b_hh,
                                               (float*)d_out);
}

// Round 16
// 223.542 us; speedup vs baseline: 1.7432x; 1.7432x over previous
//
#include <hip/hip_runtime.h>
#include <stdint.h>

typedef unsigned short u16;
typedef unsigned int u32;
typedef unsigned long long u64;
typedef __attribute__((ext_vector_type(2))) float f32x2;
typedef __attribute__((ext_vector_type(4))) float f32x4;
typedef __attribute__((ext_vector_type(8))) short s16x8;
typedef __attribute__((ext_vector_type(4))) u16 u16x4;
typedef __attribute__((ext_vector_type(2))) u32 u32x2;
typedef __attribute__((ext_vector_type(4))) u32 u32x4;

#define NS 50
#define NH 128

// k3 LDS layout (bytes):
//   hidden_tr: 8 hc x 16 t-tiles x 128B ([4t][16h] bf16 tiles) = 16384
//   M_sh:      50 rows x 512B (256 bf16, XOR-swizzled by (s&7)<<4) = 25600
//   rs:        2 x 64 f32 = 512
#define HT_OFF 0
#define M_OFF  16384
#define RS_OFF 41984
#define LDS_TOTAL 42496

// ---------- helpers ----------
__device__ __forceinline__ u16 f2bf(float f) {
  u32 u = __builtin_bit_cast(u32, f);
  u32 r = (u + 0x7FFFu + ((u >> 16) & 1u)) >> 16;
  return (u16)r;
}
__device__ __forceinline__ float bf2f(u16 u) {
  return __builtin_bit_cast(float, (u32)u << 16);
}
__device__ __forceinline__ float sigm(float x) { return 1.0f / (1.0f + __expf(-x)); }
__device__ __forceinline__ float tanh_(float x) { return 1.0f - 2.0f / (1.0f + __expf(2.0f * x)); }
__device__ __forceinline__ s16x8 pack8(f32x4 a, f32x4 b) {
  s16x8 r;
  r[0] = (short)f2bf(a[0]); r[1] = (short)f2bf(a[1]);
  r[2] = (short)f2bf(a[2]); r[3] = (short)f2bf(a[3]);
  r[4] = (short)f2bf(b[0]); r[5] = (short)f2bf(b[1]);
  r[6] = (short)f2bf(b[2]); r[7] = (short)f2bf(b[3]);
  return r;
}
// truncating f32->bf16 pack via v_perm (1 op / 2 elems); A in [0,1): err <= 2^-9
__device__ __forceinline__ s16x8 pack8_trunc(f32x4 a, f32x4 b) {
  u32x4 ua = __builtin_bit_cast(u32x4, a);
  u32x4 ub = __builtin_bit_cast(u32x4, b);
  u32x4 t;
  t[0] = __builtin_amdgcn_perm(ua[1], ua[0], 0x07060302u);
  t[1] = __builtin_amdgcn_perm(ua[3], ua[2], 0x07060302u);
  t[2] = __builtin_amdgcn_perm(ub[1], ub[0], 0x07060302u);
  t[3] = __builtin_amdgcn_perm(ub[3], ub[2], 0x07060302u);
  return __builtin_bit_cast(s16x8, t);
}

// two tr-reads -> one K=32 A-fragment ([4t][16h] tiles, col=(addr>>3)&15)
__device__ __forceinline__ s16x8 afrag_tr2(const unsigned char* p) {
  u32x2 a, b;
  asm volatile(
      "ds_read_b64_tr_b16 %0, %2\n\t"
      "ds_read_b64_tr_b16 %1, %2 offset:128\n\t"
      "s_waitcnt lgkmcnt(0)"
      : "=&v"(a), "=&v"(b)
      : "v"((const __attribute__((address_space(3))) unsigned char*)p)
      : "memory");
  __builtin_amdgcn_sched_barrier(0);
  u32x4 t; t[0] = a[0]; t[1] = a[1]; t[2] = b[0]; t[3] = b[1];
  return __builtin_bit_cast(s16x8, t);
}
// A-out B-fragment direct from global (8B-aligned f32x2 pairs, masked at col 99)
__device__ __forceinline__ s16x8 load_outfrag(const float* ap, int kbase) {
  f32x4 x = {0.f, 0.f, 0.f, 0.f}, y = {0.f, 0.f, 0.f, 0.f};
  const float* p = ap + 50 + kbase;
  if (kbase <= 40) {
    f32x2 a0 = *(const f32x2*)(p);
    f32x2 a1 = *(const f32x2*)(p + 2);
    f32x2 a2 = *(const f32x2*)(p + 4);
    f32x2 a3 = *(const f32x2*)(p + 6);
    x[0] = a0[0]; x[1] = a0[1]; x[2] = a1[0]; x[3] = a1[1];
    y[0] = a2[0]; y[1] = a2[1]; y[2] = a3[0]; y[3] = a3[1];
  } else if (kbase == 48) {
    f32x2 a0 = *(const f32x2*)(p);   // cols 98,99
    x[0] = a0[0]; x[1] = a0[1];
  }
  return pack8(x, y);
}

// Upack position for element U[j][k] (j: 0..767 = Uin|Uout, 768..1151 = Uhh; k: 0..127)
// chunk = 1KB fragment read by one wave: lane l -> 16B at chunk*1024 + l*16.
__device__ __forceinline__ int upack_pos(int j, int k) {
  int kt4 = k >> 5, g4 = (k >> 3) & 3, e2 = k & 7;
  int chunk;
  if (j < 768) {
    int big = j >= 384;
    int jj = j - big * 384;
    int gate = jj >> 7, jr = jj & 127;
    chunk = ((big * 3 + gate) * 8 + (jr >> 4)) * 4 + kt4;
    return chunk * 512 + ((g4 * 16 + (jr & 15)) * 8 + e2);
  } else {
    int jj = j - 768;
    int gate = jj >> 7, jr = jj & 127;
    chunk = 192 + (gate * 8 + (jr >> 4)) * 4 + kt4;
    return chunk * 512 + ((g4 * 16 + (jr & 15)) * 8 + e2);
  }
}

// ---------- kernel 1: fold weights -> Upack (fragment-ordered) + cvec[3][384] f32 ----------
__global__ __launch_bounds__(256) void k1_prep(
    const float* __restrict__ W_in, const float* __restrict__ b_in,
    const float* __restrict__ W_out, const float* __restrict__ b_out,
    const float* __restrict__ w_ih, const float* __restrict__ b_ih,
    const float* __restrict__ w_hh,
    const float* __restrict__ b_iah, const float* __restrict__ b_oah,
    u16* __restrict__ Upk, float* __restrict__ cvec)
{
  int e = blockIdx.x * 256 + threadIdx.x;
  if (e < 147456) {
    int j = e >> 7, k = e & 127;
    float s = 0.f;
    if (j < 768) {
      const float* wr = w_ih + (size_t)(j < 384 ? j : j - 384) * 256 + (j < 384 ? 0 : 128);
      const float* Wc = (j < 384 ? W_in : W_out) + k;
      #pragma unroll 8
      for (int h = 0; h < 128; ++h) s += wr[h] * Wc[h * 128];
    } else {
      s = w_hh[(size_t)(j - 768) * 128 + k];
    }
    Upk[upack_pos(j, k)] = f2bf(s);
  } else if (e < 147456 + 1152) {
    int e2 = e - 147456;
    int which = e2 / 384, g = e2 - which * 384;
    const float* wr = w_ih + (size_t)g * 256;
    float s = 0.f;
    if (which == 0) { for (int h = 0; h < 128; ++h) s += wr[h] * b_in[h]; }
    else if (which == 1) { for (int h = 0; h < 128; ++h) s += wr[128 + h] * b_out[h]; }
    else {
      for (int h = 0; h < 128; ++h) s += wr[h] * b_iah[h] + wr[128 + h] * b_oah[h];
      s += b_ih[g];
    }
    cvec[which * 384 + g] = s;
  }
}

// ---------- kernel 3 (v9, round-11 best: 223.9 us total): associativity + coalesced U ----------
__global__ __launch_bounds__(256, 2) void k3_main(
    const int* __restrict__ inputs, const float* __restrict__ A,
    const u16* __restrict__ Upk, const float* __restrict__ cvec,
    const float* __restrict__ emb, const float* __restrict__ b_hh,
    float* __restrict__ out)
{
  __shared__ __align__(128) unsigned char Sb[LDS_TOTAL];

  const int tid = threadIdx.x;
  const int b = blockIdx.x;
  const int w = tid >> 6, l = tid & 63;
  const int l16 = l & 15, g4 = l >> 4;

  const float* Ab = A + (size_t)b * (NS * 2 * NS);
  const int* inp = inputs + b * NS;
  float* outB = out + (size_t)b * NS * NH;
  float* rs = (float*)(Sb + RS_OFF);

  // ---- f32 rowsums (vectorized) ----
  if (tid < 100) {
    int s = tid < 50 ? tid : tid - 50;
    const float* ap = Ab + s * 100;
    float sum;
    if (tid < 50) {
      f32x4 a4 = *(const f32x4*)ap;
      #pragma unroll
      for (int q = 1; q < 12; ++q) a4 += *(const f32x4*)(ap + q * 4);
      f32x4 vt = *(const f32x4*)(ap + 48);
      sum = (a4[0] + a4[1]) + (a4[2] + a4[3]) + vt[0] + vt[1];
    } else {
      f32x4 vt = *(const f32x4*)(ap + 48);
      f32x4 a4 = *(const f32x4*)(ap + 52);
      #pragma unroll
      for (int q = 1; q < 12; ++q) a4 += *(const f32x4*)(ap + 52 + q * 4);
      sum = (a4[0] + a4[1]) + (a4[2] + a4[3]) + vt[2] + vt[3];
    }
    rs[(tid < 50 ? 0 : 64) + s] = sum;
  }

  // ---- zero tails: hidden_tr rows t>=50 (bytes [1600,2048) per hc) ----
  if (tid < 224) {
    int hc = tid / 28, q = tid - hc * 28;
    u32x4 z = {0, 0, 0, 0};
    *(u32x4*)(Sb + HT_OFF + hc * 2048 + 1600 + q * 16) = z;
  }

  // ---- stage hidden_tr: 50 emb rows (the ONLY scatter in the kernel) ----
  #pragma unroll
  for (int i = 0; i < 7; ++i) {
    int slot = i * 256 + tid;
    if (slot < 1600) {
      int t = slot >> 5, hch = slot & 31;
      int node = inp[t];
      f32x4 v = *(const f32x4*)(emb + (size_t)node * NH + hch * 4);
      u32 lo = (u32)f2bf(v[0]) | ((u32)f2bf(v[1]) << 16);
      u32 hi = (u32)f2bf(v[2]) | ((u32)f2bf(v[3]) << 16);
      u32x2 pv = {lo, hi};
      *(u32x2*)(Sb + HT_OFF + (hch >> 2) * 2048 + (t >> 2) * 128 + (t & 3) * 32 + (hch & 3) * 8) = pv;
    }
  }

  // ---- B-frags for GEMM1-in (global A cols 0..63, zero t>=50 on kt=1) ----
  s16x8 BfIn[4][2];
  #pragma unroll
  for (int nt = 0; nt < 4; ++nt) {
    int s = nt * 16 + l16; if (s > NS - 1) s = NS - 1;
    const float* ap = Ab + s * 100;
    {
      f32x4 x = *(const f32x4*)(ap + g4 * 8);
      f32x4 y = *(const f32x4*)(ap + g4 * 8 + 4);
      BfIn[nt][0] = pack8(x, y);
    }
    {
      f32x4 x = *(const f32x4*)(ap + 32 + g4 * 8);
      f32x4 y = *(const f32x4*)(ap + 32 + g4 * 8 + 4);
      int tb = 32 + g4 * 8;
      #pragma unroll
      for (int j = 0; j < 4; ++j) {
        if (tb + j >= NS) x[j] = 0.f;
        if (tb + 4 + j >= NS) y[j] = 0.f;
      }
      BfIn[nt][1] = pack8(x, y);
    }
  }
  __syncthreads();

  // ---- GEMM1: M[h][s] = hidden^T @ A_ext; write M_sh[s][h|128+h] ----
  #pragma unroll
  for (int ht2 = 0; ht2 < 2; ++ht2) {
    const int htile = w * 2 + ht2;
    f32x4 accM[2][4] = {};
    #pragma unroll
    for (int kt = 0; kt < 2; ++kt) {
      s16x8 Af = afrag_tr2(Sb + HT_OFF + htile * 2048 + (kt * 8 + 2 * g4) * 128 + l16 * 8);
      #pragma unroll
      for (int nt = 0; nt < 4; ++nt)
        accM[0][nt] = __builtin_amdgcn_mfma_f32_16x16x32_bf16(Af, BfIn[nt][kt], accM[0][nt], 0, 0, 0);
      #pragma unroll
      for (int nt = 0; nt < 4; ++nt) {
        int s = nt * 16 + l16; if (s > NS - 1) s = NS - 1;
        s16x8 Bo = load_outfrag(Ab + s * 100, kt * 32 + g4 * 8);
        accM[1][nt] = __builtin_amdgcn_mfma_f32_16x16x32_bf16(Af, Bo, accM[1][nt], 0, 0, 0);
      }
    }
    #pragma unroll
    for (int mo = 0; mo < 2; ++mo)
      #pragma unroll
      for (int nt = 0; nt < 4; ++nt) {
        int s = nt * 16 + l16;
        if (s < NS) {
          u32 colb = (u32)((mo * 128 + htile * 16 + g4 * 4) * 2);
          u32 swz = (u32)((s & 7) << 4);
          u32 lo = (u32)f2bf(accM[mo][nt][0]) | ((u32)f2bf(accM[mo][nt][1]) << 16);
          u32 hi = (u32)f2bf(accM[mo][nt][2]) | ((u32)f2bf(accM[mo][nt][3]) << 16);
          u32x2 pv = {lo, hi};
          *(u32x2*)(Sb + M_OFF + s * 512 + (colb ^ swz)) = pv;
        }
      }
  }
  __syncthreads();

  // ---- GEMM2 (gi) + GEMM3 (gh) + epilogue, per 16-col h-slice ----
  const u16* upLane = Upk + (size_t)l * 8;   // lane's 16B slot within each 1KB chunk
  #pragma unroll
  for (int ht = 0; ht < 2; ++ht) {
    const int hb = w * 32 + ht * 16;
    const int js = w * 2 + ht;
    f32x4 acc2[3][4] = {};
    f32x4 acc3[3][4] = {};
    __builtin_amdgcn_s_setprio(1);
    #pragma unroll
    for (int kt = 0; kt < 8; ++kt) {
      s16x8 Bm[4];
      #pragma unroll
      for (int nt = 0; nt < 4; ++nt) {
        int s = nt * 16 + l16; if (s > NS - 1) s = NS - 1;
        Bm[nt] = *(const s16x8*)(Sb + M_OFF + s * 512 +
                                 ((u32)(kt * 64 + g4 * 16) ^ (u32)((s & 7) << 4)));
      }
      const int big = kt >> 2, kt4 = kt & 3;
      #pragma unroll
      for (int gate = 0; gate < 3; ++gate) {
        int chunk = ((big * 3 + gate) * 8 + js) * 4 + kt4;
        s16x8 Au = *(const s16x8*)(upLane + chunk * 512);
        #pragma unroll
        for (int nt = 0; nt < 4; ++nt)
          acc2[gate][nt] = __builtin_amdgcn_mfma_f32_16x16x32_bf16(Au, Bm[nt], acc2[gate][nt], 0, 0, 0);
      }
    }
    #pragma unroll
    for (int kt = 0; kt < 4; ++kt) {
      s16x8 Bh[4];
      #pragma unroll
      for (int nt = 0; nt < 4; ++nt) {
        int s = nt * 16 + l16; if (s > NS - 1) s = NS - 1;
        int h = kt * 32 + g4 * 8;
        Bh[nt] = *(const s16x8*)(Sb + HT_OFF + (h >> 4) * 2048 + (s >> 2) * 128 +
                                 (s & 3) * 32 + (h & 15) * 2);
      }
      #pragma unroll
      for (int gate = 0; gate < 3; ++gate) {
        int chunk = 192 + (gate * 8 + js) * 4 + kt;
        s16x8 Au = *(const s16x8*)(upLane + chunk * 512);
        #pragma unroll
        for (int nt = 0; nt < 4; ++nt)
          acc3[gate][nt] = __builtin_amdgcn_mfma_f32_16x16x32_bf16(Au, Bh[nt], acc3[gate][nt], 0, 0, 0);
      }
    }
    __builtin_amdgcn_s_setprio(0);

    const int h0 = hb + g4 * 4;
    f32x4 cin[3], cou[3], cz[3], bh[3];
    #pragma unroll
    for (int gate = 0; gate < 3; ++gate) {
      int g = gate * 128 + h0;
      cin[gate] = *(const f32x4*)(cvec + g);
      cou[gate] = *(const f32x4*)(cvec + 384 + g);
      cz[gate]  = *(const f32x4*)(cvec + 768 + g);
      bh[gate]  = *(const f32x4*)(b_hh + g);
    }
    #pragma unroll
    for (int nt = 0; nt < 4; ++nt) {
      int s = nt * 16 + l16;
      int sc = s > NS - 1 ? NS - 1 : s;
      u16x4 hid4 = *(const u16x4*)(Sb + HT_OFF + (h0 >> 4) * 2048 + (sc >> 2) * 128 +
                                   (sc & 3) * 32 + (h0 & 15) * 2);
      float rin = rs[sc], rou = rs[64 + sc];
      f32x4 res;
      #pragma unroll
      for (int r = 0; r < 4; ++r) {
        float gr_ = acc3[0][nt][r] + bh[0][r];
        float gi_ = acc3[1][nt][r] + bh[1][r];
        float gn_ = acc3[2][nt][r] + bh[2][r];
        float vr = acc2[0][nt][r] + rin * cin[0][r] + rou * cou[0][r] + cz[0][r] + gr_;
        float vi = acc2[1][nt][r] + rin * cin[1][r] + rou * cou[1][r] + cz[1][r] + gi_;
        float vn = acc2[2][nt][r] + rin * cin[2][r] + rou * cou[2][r] + cz[2][r];
        float rr = sigm(vr);
        float ii = sigm(vi);
        float nn = tanh_(vn + rr * gn_);
        res[r] = nn + ii * (bf2f(hid4[r]) - nn);
      }
      if (s < NS)
        *(f32x4*)(outB + (size_t)s * NH + h0) = res;
    }
  }
}

// ---------- launcher ----------
extern "C" void kernel_launch(void* const* d_in, const int* in_sizes, int n_in,
                              void* d_out, int out_size, void* d_ws, size_t ws_size,
                              hipStream_t stream) {
  const int*   inputs = (const int*)  d_in[0];
  const float* A      = (const float*)d_in[1];
  const float* emb    = (const float*)d_in[2];
  const float* W_in   = (const float*)d_in[3];
  const float* b_in   = (const float*)d_in[4];
  const float* W_out  = (const float*)d_in[5];
  const float* b_out  = (const float*)d_in[6];
  const float* w_ih   = (const float*)d_in[7];
  const float* b_ih   = (const float*)d_in[8];
  const float* w_hh   = (const float*)d_in[9];
  const float* b_hh   = (const float*)d_in[10];
  const float* b_iah  = (const float*)d_in[11];
  const float* b_oah  = (const float*)d_in[12];

  // ws layout: Upk (1152*128 bf16 = 294,912 B, fragment-ordered) | cvec (4,608 B)
  u16*   Upk  = (u16*)d_ws;
  float* cvec = (float*)((char*)d_ws + 294912);

  k1_prep<<<dim3(581), dim3(256), 0, stream>>>(W_in, b_in, W_out, b_out, w_ih, b_ih,
                                               w_hh, b_iah, b_oah, Upk, cvec);
  k3_main<<<dim3(4096), dim3(256), 0, stream>>>(inputs, A, Upk, cvec, emb, b_hh,
                                                (float*)d_out);
}

// Round 17
// 221.180 us; speedup vs baseline: 1.7618x; 1.0107x over previous
//
#include <hip/hip_runtime.h>
#include <stdint.h>

typedef unsigned short u16;
typedef unsigned int u32;
typedef unsigned long long u64;
typedef __attribute__((ext_vector_type(2))) float f32x2;
typedef __attribute__((ext_vector_type(4))) float f32x4;
typedef __attribute__((ext_vector_type(8))) short s16x8;
typedef __attribute__((ext_vector_type(4))) u16 u16x4;
typedef __attribute__((ext_vector_type(2))) u32 u32x2;
typedef __attribute__((ext_vector_type(4))) u32 u32x4;

#define NS 50
#define NH 128

// k3 LDS layout (bytes):
//   hidden_tr: 8 hc x 16 t-tiles x 128B ([4t][16h] bf16 tiles) = 16384
//   M_sh:      50 rows x 512B (256 bf16, XOR-swizzled by (s&7)<<4) = 25600
//   rs:        2 x 64 f32 = 512
#define HT_OFF 0
#define M_OFF  16384
#define RS_OFF 41984
#define LDS_TOTAL 42496

// ---------- helpers ----------
__device__ __forceinline__ u16 f2bf(float f) {
  u32 u = __builtin_bit_cast(u32, f);
  u32 r = (u + 0x7FFFu + ((u >> 16) & 1u)) >> 16;
  return (u16)r;
}
__device__ __forceinline__ float bf2f(u16 u) {
  return __builtin_bit_cast(float, (u32)u << 16);
}
__device__ __forceinline__ float sigm(float x) { return 1.0f / (1.0f + __expf(-x)); }
__device__ __forceinline__ float tanh_(float x) { return 1.0f - 2.0f / (1.0f + __expf(2.0f * x)); }
// truncating f32->bf16 packs via v_perm (1 op / 2 elems); proven absmax-neutral (r13)
__device__ __forceinline__ s16x8 pack8_trunc(f32x4 a, f32x4 b) {
  u32x4 ua = __builtin_bit_cast(u32x4, a);
  u32x4 ub = __builtin_bit_cast(u32x4, b);
  u32x4 t;
  t[0] = __builtin_amdgcn_perm(ua[1], ua[0], 0x07060302u);
  t[1] = __builtin_amdgcn_perm(ua[3], ua[2], 0x07060302u);
  t[2] = __builtin_amdgcn_perm(ub[1], ub[0], 0x07060302u);
  t[3] = __builtin_amdgcn_perm(ub[3], ub[2], 0x07060302u);
  return __builtin_bit_cast(s16x8, t);
}
__device__ __forceinline__ u32x2 pack4_trunc(f32x4 a) {
  u32x4 ua = __builtin_bit_cast(u32x4, a);
  u32x2 t;
  t[0] = __builtin_amdgcn_perm(ua[1], ua[0], 0x07060302u);
  t[1] = __builtin_amdgcn_perm(ua[3], ua[2], 0x07060302u);
  return t;
}

// two tr-reads -> one K=32 A-fragment ([4t][16h] tiles, col=(addr>>3)&15)
__device__ __forceinline__ s16x8 afrag_tr2(const unsigned char* p) {
  u32x2 a, b;
  asm volatile(
      "ds_read_b64_tr_b16 %0, %2\n\t"
      "ds_read_b64_tr_b16 %1, %2 offset:128\n\t"
      "s_waitcnt lgkmcnt(0)"
      : "=&v"(a), "=&v"(b)
      : "v"((const __attribute__((address_space(3))) unsigned char*)p)
      : "memory");
  __builtin_amdgcn_sched_barrier(0);
  u32x4 t; t[0] = a[0]; t[1] = a[1]; t[2] = b[0]; t[3] = b[1];
  return __builtin_bit_cast(s16x8, t);
}
// A-out B-fragment direct from global (8B-aligned f32x2 pairs, masked at col 99)
__device__ __forceinline__ s16x8 load_outfrag(const float* ap, int kbase) {
  f32x4 x = {0.f, 0.f, 0.f, 0.f}, y = {0.f, 0.f, 0.f, 0.f};
  const float* p = ap + 50 + kbase;
  if (kbase <= 40) {
    f32x2 a0 = *(const f32x2*)(p);
    f32x2 a1 = *(const f32x2*)(p + 2);
    f32x2 a2 = *(const f32x2*)(p + 4);
    f32x2 a3 = *(const f32x2*)(p + 6);
    x[0] = a0[0]; x[1] = a0[1]; x[2] = a1[0]; x[3] = a1[1];
    y[0] = a2[0]; y[1] = a2[1]; y[2] = a3[0]; y[3] = a3[1];
  } else if (kbase == 48) {
    f32x2 a0 = *(const f32x2*)(p);   // cols 98,99
    x[0] = a0[0]; x[1] = a0[1];
  }
  return pack8_trunc(x, y);
}

// Upack position for element U[j][k] (j: 0..767 = Uin|Uout, 768..1151 = Uhh; k: 0..127)
// chunk = 1KB fragment read by one wave: lane l -> 16B at chunk*1024 + l*16.
__device__ __forceinline__ int upack_pos(int j, int k) {
  int kt4 = k >> 5, g4 = (k >> 3) & 3, e2 = k & 7;
  int chunk;
  if (j < 768) {
    int big = j >= 384;
    int jj = j - big * 384;
    int gate = jj >> 7, jr = jj & 127;
    chunk = ((big * 3 + gate) * 8 + (jr >> 4)) * 4 + kt4;
    return chunk * 512 + ((g4 * 16 + (jr & 15)) * 8 + e2);
  } else {
    int jj = j - 768;
    int gate = jj >> 7, jr = jj & 127;
    chunk = 192 + (gate * 8 + (jr >> 4)) * 4 + kt4;
    return chunk * 512 + ((g4 * 16 + (jr & 15)) * 8 + e2);
  }
}

// ---------- kernel 1: fold weights -> Upack (fragment-ordered) + cvec[3][384] f32 ----------
__global__ __launch_bounds__(256) void k1_prep(
    const float* __restrict__ W_in, const float* __restrict__ b_in,
    const float* __restrict__ W_out, const float* __restrict__ b_out,
    const float* __restrict__ w_ih, const float* __restrict__ b_ih,
    const float* __restrict__ w_hh,
    const float* __restrict__ b_iah, const float* __restrict__ b_oah,
    u16* __restrict__ Upk, float* __restrict__ cvec)
{
  int e = blockIdx.x * 256 + threadIdx.x;
  if (e < 147456) {
    int j = e >> 7, k = e & 127;
    float s = 0.f;
    if (j < 768) {
      const float* wr = w_ih + (size_t)(j < 384 ? j : j - 384) * 256 + (j < 384 ? 0 : 128);
      const float* Wc = (j < 384 ? W_in : W_out) + k;
      #pragma unroll 8
      for (int h = 0; h < 128; ++h) s += wr[h] * Wc[h * 128];
    } else {
      s = w_hh[(size_t)(j - 768) * 128 + k];
    }
    Upk[upack_pos(j, k)] = f2bf(s);
  } else if (e < 147456 + 1152) {
    int e2 = e - 147456;
    int which = e2 / 384, g = e2 - which * 384;
    const float* wr = w_ih + (size_t)g * 256;
    float s = 0.f;
    if (which == 0) { for (int h = 0; h < 128; ++h) s += wr[h] * b_in[h]; }
    else if (which == 1) { for (int h = 0; h < 128; ++h) s += wr[128 + h] * b_out[h]; }
    else {
      for (int h = 0; h < 128; ++h) s += wr[h] * b_iah[h] + wr[128 + h] * b_oah[h];
      s += b_ih[g];
    }
    cvec[which * 384 + g] = s;
  }
}

// ---------- kernel 3 (v9.1): r16 + truncating packs on BfIn / outfrag / staging ----------
__global__ __launch_bounds__(256, 2) void k3_main(
    const int* __restrict__ inputs, const float* __restrict__ A,
    const u16* __restrict__ Upk, const float* __restrict__ cvec,
    const float* __restrict__ emb, const float* __restrict__ b_hh,
    float* __restrict__ out)
{
  __shared__ __align__(128) unsigned char Sb[LDS_TOTAL];

  const int tid = threadIdx.x;
  const int b = blockIdx.x;
  const int w = tid >> 6, l = tid & 63;
  const int l16 = l & 15, g4 = l >> 4;

  const float* Ab = A + (size_t)b * (NS * 2 * NS);
  const int* inp = inputs + b * NS;
  float* outB = out + (size_t)b * NS * NH;
  float* rs = (float*)(Sb + RS_OFF);

  // ---- f32 rowsums (vectorized) ----
  if (tid < 100) {
    int s = tid < 50 ? tid : tid - 50;
    const float* ap = Ab + s * 100;
    float sum;
    if (tid < 50) {
      f32x4 a4 = *(const f32x4*)ap;
      #pragma unroll
      for (int q = 1; q < 12; ++q) a4 += *(const f32x4*)(ap + q * 4);
      f32x4 vt = *(const f32x4*)(ap + 48);
      sum = (a4[0] + a4[1]) + (a4[2] + a4[3]) + vt[0] + vt[1];
    } else {
      f32x4 vt = *(const f32x4*)(ap + 48);
      f32x4 a4 = *(const f32x4*)(ap + 52);
      #pragma unroll
      for (int q = 1; q < 12; ++q) a4 += *(const f32x4*)(ap + 52 + q * 4);
      sum = (a4[0] + a4[1]) + (a4[2] + a4[3]) + vt[2] + vt[3];
    }
    rs[(tid < 50 ? 0 : 64) + s] = sum;
  }

  // ---- zero tails: hidden_tr rows t>=50 (bytes [1600,2048) per hc) ----
  if (tid < 224) {
    int hc = tid / 28, q = tid - hc * 28;
    u32x4 z = {0, 0, 0, 0};
    *(u32x4*)(Sb + HT_OFF + hc * 2048 + 1600 + q * 16) = z;
  }

  // ---- stage hidden_tr: 50 emb rows (the ONLY scatter in the kernel) ----
  #pragma unroll
  for (int i = 0; i < 7; ++i) {
    int slot = i * 256 + tid;
    if (slot < 1600) {
      int t = slot >> 5, hch = slot & 31;
      int node = inp[t];
      f32x4 v = *(const f32x4*)(emb + (size_t)node * NH + hch * 4);
      u32x2 pv = pack4_trunc(v);
      *(u32x2*)(Sb + HT_OFF + (hch >> 2) * 2048 + (t >> 2) * 128 + (t & 3) * 32 + (hch & 3) * 8) = pv;
    }
  }

  // ---- B-frags for GEMM1-in (global A cols 0..63, zero t>=50 on kt=1) ----
  s16x8 BfIn[4][2];
  #pragma unroll
  for (int nt = 0; nt < 4; ++nt) {
    int s = nt * 16 + l16; if (s > NS - 1) s = NS - 1;
    const float* ap = Ab + s * 100;
    {
      f32x4 x = *(const f32x4*)(ap + g4 * 8);
      f32x4 y = *(const f32x4*)(ap + g4 * 8 + 4);
      BfIn[nt][0] = pack8_trunc(x, y);
    }
    {
      f32x4 x = *(const f32x4*)(ap + 32 + g4 * 8);
      f32x4 y = *(const f32x4*)(ap + 32 + g4 * 8 + 4);
      int tb = 32 + g4 * 8;
      #pragma unroll
      for (int j = 0; j < 4; ++j) {
        if (tb + j >= NS) x[j] = 0.f;
        if (tb + 4 + j >= NS) y[j] = 0.f;
      }
      BfIn[nt][1] = pack8_trunc(x, y);
    }
  }
  __syncthreads();

  // ---- GEMM1: M[h][s] = hidden^T @ A_ext; write M_sh[s][h|128+h] ----
  #pragma unroll
  for (int ht2 = 0; ht2 < 2; ++ht2) {
    const int htile = w * 2 + ht2;
    f32x4 accM[2][4] = {};
    #pragma unroll
    for (int kt = 0; kt < 2; ++kt) {
      s16x8 Af = afrag_tr2(Sb + HT_OFF + htile * 2048 + (kt * 8 + 2 * g4) * 128 + l16 * 8);
      #pragma unroll
      for (int nt = 0; nt < 4; ++nt)
        accM[0][nt] = __builtin_amdgcn_mfma_f32_16x16x32_bf16(Af, BfIn[nt][kt], accM[0][nt], 0, 0, 0);
      #pragma unroll
      for (int nt = 0; nt < 4; ++nt) {
        int s = nt * 16 + l16; if (s > NS - 1) s = NS - 1;
        s16x8 Bo = load_outfrag(Ab + s * 100, kt * 32 + g4 * 8);
        accM[1][nt] = __builtin_amdgcn_mfma_f32_16x16x32_bf16(Af, Bo, accM[1][nt], 0, 0, 0);
      }
    }
    #pragma unroll
    for (int mo = 0; mo < 2; ++mo)
      #pragma unroll
      for (int nt = 0; nt < 4; ++nt) {
        int s = nt * 16 + l16;
        if (s < NS) {
          u32 colb = (u32)((mo * 128 + htile * 16 + g4 * 4) * 2);
          u32 swz = (u32)((s & 7) << 4);
          u32 lo = (u32)f2bf(accM[mo][nt][0]) | ((u32)f2bf(accM[mo][nt][1]) << 16);
          u32 hi = (u32)f2bf(accM[mo][nt][2]) | ((u32)f2bf(accM[mo][nt][3]) << 16);
          u32x2 pv = {lo, hi};
          *(u32x2*)(Sb + M_OFF + s * 512 + (colb ^ swz)) = pv;
        }
      }
  }
  __syncthreads();

  // ---- GEMM2 (gi) + GEMM3 (gh) + epilogue, per 16-col h-slice ----
  const u16* upLane = Upk + (size_t)l * 8;   // lane's 16B slot within each 1KB chunk
  #pragma unroll
  for (int ht = 0; ht < 2; ++ht) {
    const int hb = w * 32 + ht * 16;
    const int js = w * 2 + ht;
    f32x4 acc2[3][4] = {};
    f32x4 acc3[3][4] = {};
    __builtin_amdgcn_s_setprio(1);
    #pragma unroll
    for (int kt = 0; kt < 8; ++kt) {
      s16x8 Bm[4];
      #pragma unroll
      for (int nt = 0; nt < 4; ++nt) {
        int s = nt * 16 + l16; if (s > NS - 1) s = NS - 1;
        Bm[nt] = *(const s16x8*)(Sb + M_OFF + s * 512 +
                                 ((u32)(kt * 64 + g4 * 16) ^ (u32)((s & 7) << 4)));
      }
      const int big = kt >> 2, kt4 = kt & 3;
      #pragma unroll
      for (int gate = 0; gate < 3; ++gate) {
        int chunk = ((big * 3 + gate) * 8 + js) * 4 + kt4;
        s16x8 Au = *(const s16x8*)(upLane + chunk * 512);
        #pragma unroll
        for (int nt = 0; nt < 4; ++nt)
          acc2[gate][nt] = __builtin_amdgcn_mfma_f32_16x16x32_bf16(Au, Bm[nt], acc2[gate][nt], 0, 0, 0);
      }
    }
    #pragma unroll
    for (int kt = 0; kt < 4; ++kt) {
      s16x8 Bh[4];
      #pragma unroll
      for (int nt = 0; nt < 4; ++nt) {
        int s = nt * 16 + l16; if (s > NS - 1) s = NS - 1;
        int h = kt * 32 + g4 * 8;
        Bh[nt] = *(const s16x8*)(Sb + HT_OFF + (h >> 4) * 2048 + (s >> 2) * 128 +
                                 (s & 3) * 32 + (h & 15) * 2);
      }
      #pragma unroll
      for (int gate = 0; gate < 3; ++gate) {
        int chunk = 192 + (gate * 8 + js) * 4 + kt;
        s16x8 Au = *(const s16x8*)(upLane + chunk * 512);
        #pragma unroll
        for (int nt = 0; nt < 4; ++nt)
          acc3[gate][nt] = __builtin_amdgcn_mfma_f32_16x16x32_bf16(Au, Bh[nt], acc3[gate][nt], 0, 0, 0);
      }
    }
    __builtin_amdgcn_s_setprio(0);

    const int h0 = hb + g4 * 4;
    f32x4 cin[3], cou[3], cz[3], bh[3];
    #pragma unroll
    for (int gate = 0; gate < 3; ++gate) {
      int g = gate * 128 + h0;
      cin[gate] = *(const f32x4*)(cvec + g);
      cou[gate] = *(const f32x4*)(cvec + 384 + g);
      cz[gate]  = *(const f32x4*)(cvec + 768 + g);
      bh[gate]  = *(const f32x4*)(b_hh + g);
    }
    #pragma unroll
    for (int nt = 0; nt < 4; ++nt) {
      int s = nt * 16 + l16;
      int sc = s > NS - 1 ? NS - 1 : s;
      u16x4 hid4 = *(const u16x4*)(Sb + HT_OFF + (h0 >> 4) * 2048 + (sc >> 2) * 128 +
                                   (sc & 3) * 32 + (h0 & 15) * 2);
      float rin = rs[sc], rou = rs[64 + sc];
      f32x4 res;
      #pragma unroll
      for (int r = 0; r < 4; ++r) {
        float gr_ = acc3[0][nt][r] + bh[0][r];
        float gi_ = acc3[1][nt][r] + bh[1][r];
        float gn_ = acc3[2][nt][r] + bh[2][r];
        float vr = acc2[0][nt][r] + rin * cin[0][r] + rou * cou[0][r] + cz[0][r] + gr_;
        float vi = acc2[1][nt][r] + rin * cin[1][r] + rou * cou[1][r] + cz[1][r] + gi_;
        float vn = acc2[2][nt][r] + rin * cin[2][r] + rou * cou[2][r] + cz[2][r];
        float rr = sigm(vr);
        float ii = sigm(vi);
        float nn = tanh_(vn + rr * gn_);
        res[r] = nn + ii * (bf2f(hid4[r]) - nn);
      }
      if (s < NS)
        *(f32x4*)(outB + (size_t)s * NH + h0) = res;
    }
  }
}

// ---------- launcher ----------
extern "C" void kernel_launch(void* const* d_in, const int* in_sizes, int n_in,
                              void* d_out, int out_size, void* d_ws, size_t ws_size,
                              hipStream_t stream) {
  const int*   inputs = (const int*)  d_in[0];
  const float* A      = (const float*)d_in[1];
  const float* emb    = (const float*)d_in[2];
  const float* W_in   = (const float*)d_in[3];
  const float* b_in   = (const float*)d_in[4];
  const float* W_out  = (const float*)d_in[5];
  const float* b_out  = (const float*)d_in[6];
  const float* w_ih   = (const float*)d_in[7];
  const float* b_ih   = (const float*)d_in[8];
  const float* w_hh   = (const float*)d_in[9];
  const float* b_hh   = (const float*)d_in[10];
  const float* b_iah  = (const float*)d_in[11];
  const float* b_oah  = (const float*)d_in[12];

  // ws layout: Upk (1152*128 bf16 = 294,912 B, fragment-ordered) | cvec (4,608 B)
  u16*   Upk  = (u16*)d_ws;
  float* cvec = (float*)((char*)d_ws + 294912);

  k1_prep<<<dim3(581), dim3(256), 0, stream>>>(W_in, b_in, W_out, b_out, w_ih, b_ih,
                                               w_hh, b_iah, b_oah, Upk, cvec);
  k3_main<<<dim3(4096), dim3(256), 0, stream>>>(inputs, A, Upk, cvec, emb, b_hh,
                                                (float*)d_out);
}